// Round 12
// baseline (149.629 us; speedup 1.0000x reference)
//
#include <hip/hip_runtime.h>

// Pipeline: mask_pack (clean standalone ballot streamer) -> prep_w -> qkv_gemm (pure
//           fused Q,K,V GEMM; K & V^T written XOR-swizzled) -> attn (flash, dbuf LDS
//           K/V + counted vmcnt, packed u64 mask words prefetched one tile ahead)
//           -> out_gemm
// All matmul compute in bf16 MFMA (16x16x32), f32 accumulate. Output f32.

typedef __attribute__((ext_vector_type(4))) float    f32x4;
typedef __attribute__((ext_vector_type(8))) short    s16x8;
typedef __attribute__((ext_vector_type(4))) short    s16x4;
typedef unsigned long long u64;

__device__ __forceinline__ short f2b(float f) {
    union { float f; unsigned u; } v; v.f = f;
    unsigned r = v.u + 0x7FFFu + ((v.u >> 16) & 1u);
    return (short)(r >> 16);
}

__device__ __forceinline__ void gl_lds16(const short* g, short* l) {
    __builtin_amdgcn_global_load_lds(
        (const __attribute__((address_space(1))) unsigned int*)g,
        (__attribute__((address_space(3))) unsigned int*)l, 16, 0, 0);
}

// ---- standalone mask bit-pack: pure streamer, full occupancy, nothing co-resident ----
// Packed format (validated r6/r7): word(r,ch,c) at mp[r*16+ch*4+c],
// bit l = (mask[r*1024 + ch*256 + 4l + c] != 0).
// 4096 blocks x 4 waves; each wave: 2 rows (8KB) -- 8 independent f32x4 loads issued
// before any ballot, 32 ballots, 2 x 128B contiguous stores (lanes 0..15).
__global__ __launch_bounds__(256) void mask_pack(const float* __restrict__ m,
                                                 u64* __restrict__ mp) {
    const int wgid = blockIdx.x * 4 + (threadIdx.x >> 6);   // 16384 waves
    const int l = threadIdx.x & 63;
    const size_t E0 = (size_t)wgid * 2048;                  // two 1024-elem rows
    f32x4 v[2][4];
    #pragma unroll
    for (int r = 0; r < 2; ++r)
        #pragma unroll
        for (int c = 0; c < 4; ++c)
            v[r][c] = *(const f32x4*)(m + E0 + (size_t)r * 1024 + c * 256 + l * 4);
    #pragma unroll
    for (int r = 0; r < 2; ++r) {
        u64 w = 0;
        #pragma unroll
        for (int c = 0; c < 4; ++c) {
            u64 b0 = __ballot(v[r][c].x != 0.f);
            u64 b1 = __ballot(v[r][c].y != 0.f);
            u64 b2 = __ballot(v[r][c].z != 0.f);
            u64 b3 = __ballot(v[r][c].w != 0.f);
            if ((l >> 2) == c) {
                int cc = l & 3;
                w = (cc == 0) ? b0 : (cc == 1) ? b1 : (cc == 2) ? b2 : b3;
            }
        }
        if (l < 16) mp[((E0 >> 10) + r) * 16 + l] = w;
    }
}

// ---- Wt[w][n][k] = (bf16) W_w[k][n], w order {q,k,v,o} ----
__global__ void prep_w(const float* __restrict__ Wq, const float* __restrict__ Wk,
                       const float* __restrict__ Wv, const float* __restrict__ Wo,
                       short* __restrict__ Wt) {
    int idx = blockIdx.x * 256 + threadIdx.x;       // 4 * 65536 total
    int w = idx >> 16, rem = idx & 65535;
    int n = rem >> 8, kk = rem & 255;
    const float* W = (w == 0) ? Wq : (w == 1) ? Wk : (w == 2) ? Wv : Wo;
    Wt[idx] = f2b(W[kk * 256 + n]);
}

// ---- fused QKV projection: x[32768,256] f32 @ W^T -> relu -> bf16 ----
// q stored [seq][h] linear; k stored [seq][h] with 16B-chunk low3 XOR (seq&7);
// v stored transposed Vt[b][h][seq] with 16B-chunk low3 XOR (h&7).
__global__ __launch_bounds__(256) void qkv_gemm(
        const float* __restrict__ x, const short* __restrict__ Wt,
        const float* __restrict__ bq, const float* __restrict__ bk, const float* __restrict__ bv,
        short* __restrict__ qO, short* __restrict__ kO, short* __restrict__ vtO) {
    __shared__ short a_lds[128][72];        // x tile bf16 (also reused as epilogue bounce)
    __shared__ short b_lds[3][64][72];      // W^T tiles
    const int tid = threadIdx.x;
    const int bm = blockIdx.x >> 2, bn = blockIdx.x & 3;
    const int s0 = bm * 128, n0 = bn * 64;
    const int wid = tid >> 6, l = tid & 63, lo4 = l & 15, hi4 = l >> 4;
    const int wm = wid >> 1, wn = wid & 1;

    f32x4 acc[3][4][2];
    #pragma unroll
    for (int w = 0; w < 3; ++w)
        #pragma unroll
        for (int mi = 0; mi < 4; ++mi)
            #pragma unroll
            for (int ni = 0; ni < 2; ++ni)
                acc[w][mi][ni] = (f32x4){0.f, 0.f, 0.f, 0.f};

    for (int kt = 0; kt < 4; ++kt) {
        const int k0 = kt * 64;
        #pragma unroll
        for (int i = 0; i < 8; ++i) {                       // stage A: 128x64 f32 -> bf16
            int ch = i * 256 + tid;
            int row = ch >> 4, c4 = (ch & 15) * 4;
            f32x4 xv = *(const f32x4*)(x + (size_t)(s0 + row) * 256 + k0 + c4);
            s16x4 pk = { f2b(xv.x), f2b(xv.y), f2b(xv.z), f2b(xv.w) };
            *(s16x4*)&a_lds[row][c4] = pk;
        }
        #pragma unroll
        for (int w = 0; w < 3; ++w) {                       // stage B: 3 x 64x64 bf16
            #pragma unroll
            for (int i = 0; i < 2; ++i) {
                int ch = i * 256 + tid;
                int n = ch >> 3, c8 = (ch & 7) * 8;
                *(s16x8*)&b_lds[w][n][c8] =
                    *(const s16x8*)(Wt + (size_t)w * 65536 + (size_t)(n0 + n) * 256 + k0 + c8);
            }
        }
        __syncthreads();
        s16x8 af[4][2];
        #pragma unroll
        for (int mi = 0; mi < 4; ++mi)
            #pragma unroll
            for (int kk = 0; kk < 2; ++kk)
                af[mi][kk] = *(s16x8*)&a_lds[wm * 64 + mi * 16 + lo4][kk * 32 + hi4 * 8];
        #pragma unroll
        for (int w = 0; w < 3; ++w)
            #pragma unroll
            for (int ni = 0; ni < 2; ++ni)
                #pragma unroll
                for (int kk = 0; kk < 2; ++kk) {
                    s16x8 bfr = *(s16x8*)&b_lds[w][wn * 32 + ni * 16 + lo4][kk * 32 + hi4 * 8];
                    #pragma unroll
                    for (int mi = 0; mi < 4; ++mi)
                        acc[w][mi][ni] = __builtin_amdgcn_mfma_f32_16x16x32_bf16(
                            af[mi][kk], bfr, acc[w][mi][ni], 0, 0, 0);
                }
        __syncthreads();
    }

    const float* bias[3] = { bq, bk, bv };
    for (int w = 0; w < 3; ++w) {
        #pragma unroll
        for (int mi = 0; mi < 4; ++mi)
            #pragma unroll
            for (int ni = 0; ni < 2; ++ni)
                #pragma unroll
                for (int j = 0; j < 4; ++j) {
                    int r = wm * 64 + mi * 16 + hi4 * 4 + j;
                    int c = wn * 32 + ni * 16 + lo4;
                    float v = acc[w][mi][ni][j] + bias[w][n0 + c];
                    a_lds[r][c] = f2b(fmaxf(v, 0.f));
                }
        __syncthreads();
        if (w == 0) {
            #pragma unroll
            for (int i = 0; i < 4; ++i) {
                int ch = i * 256 + tid;
                int row = ch >> 3, c8 = (ch & 7) * 8;
                *(s16x8*)(qO + (size_t)(s0 + row) * 256 + n0 + c8) = *(s16x8*)&a_lds[row][c8];
            }
        } else if (w == 1) {
            #pragma unroll
            for (int i = 0; i < 4; ++i) {
                int ch = i * 256 + tid;
                int row = ch >> 3, c8 = (ch & 7) * 8;
                int swz = ((c8 >> 3) ^ (row & 7)) * 8;      // seq-keyed chunk XOR
                *(s16x8*)(kO + (size_t)(s0 + row) * 256 + n0 + swz) = *(s16x8*)&a_lds[row][c8];
            }
        } else {
            int bb = s0 >> 10, nn = s0 & 1023;              // block spans a single batch
            #pragma unroll
            for (int i = 0; i < 4; ++i) {
                int ch = i * 256 + tid;
                int h = ch >> 4, sc = (ch & 15) * 8;
                s16x8 t;
                #pragma unroll
                for (int e = 0; e < 8; ++e) t[e] = a_lds[sc + e][h];
                int cil = sc >> 3;                          // 0..15
                int swz = (cil & 8) | ((cil & 7) ^ ((n0 + h) & 7));   // h-keyed chunk XOR
                *(s16x8*)(vtO + ((size_t)bb * 256 + n0 + h) * 1024 + nn + swz * 8) = t;
            }
        }
        __syncthreads();
    }
}

// ---- flash attention: 8 waves/block, Q-tile 128, double-buffered K/V, counted vmcnt ----
// Mask: packed u64 words, 4 loads/lane/kt through the prefetch pipeline (r6-validated).
__global__ __launch_bounds__(512) void attn(
        const short* __restrict__ q, const short* __restrict__ k,
        const short* __restrict__ vt, const u64* __restrict__ mp64,
        short* __restrict__ attv) {
    __shared__ short kbuf[2][16384];        // 2 x K[64][256] (row-XOR-swizzled layout)
    __shared__ short vbuf[2][16384];        // 2 x V[256][64] (h-XOR-swizzled layout)
    __shared__ short p_lds[8][16][72];      // per-wave P relayout / epilogue bounce
    const int tid = threadIdx.x, wid = tid >> 6, l = tid & 63;
    const int lo4 = l & 15, hi4 = l >> 4;
    const int bid = blockIdx.x;
    const int swz = (bid & 7) * 32 + (bid >> 3);    // XCD-chunked: 4 batches per XCD
    const int b = swz >> 3, qb = swz & 7;
    const int q0 = qb * 128 + wid * 16;
    const size_t bq_row = (size_t)b * 1024 + q0;

    const short* kb  = k  + (size_t)b * 1024 * 256;
    const short* vtg = vt + (size_t)b * 256 * 1024;
    // per-lane word base: row (q0+hi4*4+j), comp lo4&3
    const u64* mwb = mp64 + ((size_t)b * 1024 + q0 + hi4 * 4) * 16 + (lo4 & 3);

#define STAGE_K(bufi, c0_) do { const short* sg_ = kb + (size_t)(c0_) * 256;          \
    _Pragma("unroll") for (int i_ = 0; i_ < 4; ++i_) { int cb_ = i_ * 512 + wid * 64; \
        gl_lds16(sg_ + (size_t)(cb_ + l) * 8, &kbuf[bufi][cb_ * 8]); } } while (0)
#define STAGE_V(bufi, c0_) do {                                                       \
    _Pragma("unroll") for (int i_ = 0; i_ < 4; ++i_) { int cb_ = i_ * 512 + wid * 64; \
        int ch_ = cb_ + l; int h_ = ch_ >> 3, cc_ = ch_ & 7;                          \
        gl_lds16(vtg + (size_t)h_ * 1024 + (c0_) + cc_ * 8, &vbuf[bufi][cb_ * 8]); } } while (0)
// 4 u64 loads: dst[j] = word(row q0+hi4*4+j, chunk t>>2, comp lo4&3)
#define LOAD_MASK(dst, t_) do {                                                       \
    _Pragma("unroll") for (int j_ = 0; j_ < 4; ++j_)                                  \
        dst[j_] = mwb[(size_t)j_ * 16 + ((t_) >> 2) * 4]; } while (0)

    s16x8 qf[8];
    {
        const short* qp = q + (bq_row + lo4) * 256 + hi4 * 8;
        #pragma unroll
        for (int t = 0; t < 8; ++t) qf[t] = *(const s16x8*)(qp + t * 32);
    }
    f32x4 oacc[16];
    #pragma unroll
    for (int t = 0; t < 16; ++t) oacc[t] = (f32x4){0.f, 0.f, 0.f, 0.f};
    float m_run[4] = { -1e30f, -1e30f, -1e30f, -1e30f };
    float l_run[4] = { 0.f, 0.f, 0.f, 0.f };
    u64 mkc[4], mkn[4];                     // mask word dbuf

    // prologue: stage tile 0 (K: 4 loads, mask: 4, V: 4)
    STAGE_K(0, 0);
    LOAD_MASK(mkc, 0);
    STAGE_V(0, 0);

    for (int t = 0; t < 16; ++t) {
        const int cur = t & 1;
        const int c0 = t * 64;
        // ---- issue next K stage + next mask, then wait for K[t] (counted) ----
        if (t < 15) {
            STAGE_K(cur ^ 1, c0 + 64);                      // +4 vmem
            LOAD_MASK(mkn, t + 1);                          // +4 vmem
            // younger-than-K[t]: mask[t](4) + V[t](4) + K[t+1](4) + mask[t+1](4) = 16
            asm volatile("s_waitcnt vmcnt(16)" ::: "memory");
        } else {
            // younger-than-K[15]: mask[15](4) + V[15](4) = 8
            asm volatile("s_waitcnt vmcnt(8)" ::: "memory");
        }
        __builtin_amdgcn_s_barrier();
        // ---- QK^T on kbuf[cur] ----
        f32x4 s[4];
        #pragma unroll
        for (int ct = 0; ct < 4; ++ct) s[ct] = (f32x4){0.f, 0.f, 0.f, 0.f};
        __builtin_amdgcn_s_setprio(1);
        #pragma unroll
        for (int ct = 0; ct < 4; ++ct) {
            int row = ct * 16 + lo4, rx = row & 7;
            #pragma unroll
            for (int tt = 0; tt < 8; ++tt) {
                int ch = tt * 4 + hi4;
                int sc = (ch & 24) | ((ch & 7) ^ rx);
                s16x8 kf = *(s16x8*)&kbuf[cur][row * 256 + sc * 8];
                s[ct] = __builtin_amdgcn_mfma_f32_16x16x32_bf16(qf[tt], kf, s[ct], 0, 0, 0);
            }
        }
        __builtin_amdgcn_s_setprio(0);
        // ---- masked online softmax (packed bits in regs) ----
        const unsigned shx = ((unsigned)(t & 3) << 4) | (unsigned)(lo4 >> 2);
        float sm[4][4];
        #pragma unroll
        for (int j = 0; j < 4; ++j) {
            unsigned wsx = (unsigned)(mkc[j] >> shx);
            sm[0][j] = (wsx & 1u)     ? s[0][j] : -1e30f;
            sm[1][j] = (wsx & 16u)    ? s[1][j] : -1e30f;
            sm[2][j] = (wsx & 256u)   ? s[2][j] : -1e30f;
            sm[3][j] = (wsx & 4096u)  ? s[3][j] : -1e30f;
        }
        float scale[4], p[4][4];
        #pragma unroll
        for (int j = 0; j < 4; ++j) {
            float tmx = fmaxf(fmaxf(sm[0][j], sm[1][j]), fmaxf(sm[2][j], sm[3][j]));
            tmx = fmaxf(tmx, __shfl_xor(tmx, 1));
            tmx = fmaxf(tmx, __shfl_xor(tmx, 2));
            tmx = fmaxf(tmx, __shfl_xor(tmx, 4));
            tmx = fmaxf(tmx, __shfl_xor(tmx, 8));
            float mnew = fmaxf(m_run[j], tmx);
            scale[j] = __expf(m_run[j] - mnew);
            m_run[j] = mnew;
            float su = 0.f;
            #pragma unroll
            for (int ct = 0; ct < 4; ++ct) { p[ct][j] = __expf(sm[ct][j] - mnew); su += p[ct][j]; }
            su += __shfl_xor(su, 1);
            su += __shfl_xor(su, 2);
            su += __shfl_xor(su, 4);
            su += __shfl_xor(su, 8);
            l_run[j] = l_run[j] * scale[j] + su;
        }
        #pragma unroll
        for (int tt = 0; tt < 16; ++tt)
            #pragma unroll
            for (int j = 0; j < 4; ++j) oacc[tt][j] *= scale[j];
        // ---- P (D-layout) -> per-wave LDS -> A-fragment ----
        #pragma unroll
        for (int ct = 0; ct < 4; ++ct)
            #pragma unroll
            for (int j = 0; j < 4; ++j)
                p_lds[wid][hi4 * 4 + j][ct * 16 + lo4] = f2b(p[ct][j]);
        asm volatile("s_waitcnt lgkmcnt(0)" ::: "memory");
        __builtin_amdgcn_sched_barrier(0);
        s16x8 pa0 = *(s16x8*)&p_lds[wid][lo4][hi4 * 8];
        s16x8 pa1 = *(s16x8*)&p_lds[wid][lo4][32 + hi4 * 8];
        // ---- issue next V stage, then wait for V[t] (counted) ----
        if (t < 15) {
            STAGE_V(cur ^ 1, c0 + 64);                      // +4 vmem
            // younger-than-V[t]: K[t+1](4) + mask[t+1](4) + V[t+1](4) = 12
            asm volatile("s_waitcnt vmcnt(12)" ::: "memory");
        } else {
            asm volatile("s_waitcnt vmcnt(0)" ::: "memory");
        }
        __builtin_amdgcn_s_barrier();
        // ---- PV on vbuf[cur] ----
        __builtin_amdgcn_s_setprio(1);
        #pragma unroll
        for (int nt = 0; nt < 16; ++nt) {
            int h = nt * 16 + lo4, hx = h & 7;
            s16x8 vf0 = *(s16x8*)&vbuf[cur][h * 64 + (hi4 ^ hx) * 8];
            s16x8 vf1 = *(s16x8*)&vbuf[cur][h * 64 + ((hi4 + 4) ^ hx) * 8];
            oacc[nt] = __builtin_amdgcn_mfma_f32_16x16x32_bf16(pa0, vf0, oacc[nt], 0, 0, 0);
            oacc[nt] = __builtin_amdgcn_mfma_f32_16x16x32_bf16(pa1, vf1, oacc[nt], 0, 0, 0);
        }
        __builtin_amdgcn_s_setprio(0);
        // ---- rotate mask regs ----
        if (t < 15) {
            #pragma unroll
            for (int i = 0; i < 4; ++i) mkc[i] = mkn[i];
        }
    }
    // ---- epilogue: normalize, bf16, coalesced store via per-wave LDS (4 passes) ----
    float inv[4];
    #pragma unroll
    for (int j = 0; j < 4; ++j) inv[j] = 1.f / l_run[j];
    #pragma unroll
    for (int g = 0; g < 4; ++g) {
        asm volatile("s_waitcnt lgkmcnt(0)" ::: "memory");  // prior pass reads done
        #pragma unroll
        for (int ntl = 0; ntl < 4; ++ntl)
            #pragma unroll
            for (int j = 0; j < 4; ++j)
                p_lds[wid][hi4 * 4 + j][ntl * 16 + lo4] = f2b(oacc[g * 4 + ntl][j] * inv[j]);
        asm volatile("s_waitcnt lgkmcnt(0)" ::: "memory");
        __builtin_amdgcn_sched_barrier(0);
        s16x8 r0 = *(s16x8*)&p_lds[wid][lo4][hi4 * 16];
        s16x8 r1 = *(s16x8*)&p_lds[wid][lo4][hi4 * 16 + 8];
        short* op = attv + (bq_row + lo4) * 256 + g * 64 + hi4 * 16;
        *(s16x8*)op = r0;
        *(s16x8*)(op + 8) = r1;
    }
#undef STAGE_K
#undef STAGE_V
#undef LOAD_MASK
}

// ---- output GEMM: attv bf16 @ Wo^T + bo -> relu -> f32 ----
__global__ __launch_bounds__(256) void out_gemm(
        const short* __restrict__ a, const short* __restrict__ Wto,
        const float* __restrict__ bo, float* __restrict__ out) {
    __shared__ short a_lds[128][72];
    __shared__ short b_lds[64][72];
    __shared__ float bounce[128][68];
    const int tid = threadIdx.x;
    const int bm = blockIdx.x >> 2, bn = blockIdx.x & 3;
    const int s0 = bm * 128, n0 = bn * 64;
    const int wid = tid >> 6, l = tid & 63, lo4 = l & 15, hi4 = l >> 4;
    const int wm = wid >> 1, wn = wid & 1;
    f32x4 acc[4][2];
    #pragma unroll
    for (int mi = 0; mi < 4; ++mi)
        #pragma unroll
        for (int ni = 0; ni < 2; ++ni) acc[mi][ni] = (f32x4){0.f, 0.f, 0.f, 0.f};

    for (int kt = 0; kt < 4; ++kt) {
        const int k0 = kt * 64;
        #pragma unroll
        for (int i = 0; i < 4; ++i) {
            int ch = i * 256 + tid;
            int row = ch >> 3, c8 = (ch & 7) * 8;
            *(s16x8*)&a_lds[row][c8] = *(const s16x8*)(a + (size_t)(s0 + row) * 256 + k0 + c8);
        }
        #pragma unroll
        for (int i = 0; i < 2; ++i) {
            int ch = i * 256 + tid;
            int n = ch >> 3, c8 = (ch & 7) * 8;
            *(s16x8*)&b_lds[n][c8] = *(const s16x8*)(Wto + (size_t)(n0 + n) * 256 + k0 + c8);
        }
        __syncthreads();
        s16x8 af[4][2];
        #pragma unroll
        for (int mi = 0; mi < 4; ++mi)
            #pragma unroll
            for (int kk = 0; kk < 2; ++kk)
                af[mi][kk] = *(s16x8*)&a_lds[wm * 64 + mi * 16 + lo4][kk * 32 + hi4 * 8];
        #pragma unroll
        for (int ni = 0; ni < 2; ++ni)
            #pragma unroll
            for (int kk = 0; kk < 2; ++kk) {
                s16x8 bfr = *(s16x8*)&b_lds[wn * 32 + ni * 16 + lo4][kk * 32 + hi4 * 8];
                #pragma unroll
                for (int mi = 0; mi < 4; ++mi)
                    acc[mi][ni] = __builtin_amdgcn_mfma_f32_16x16x32_bf16(
                        af[mi][kk], bfr, acc[mi][ni], 0, 0, 0);
            }
        __syncthreads();
    }
    #pragma unroll
    for (int mi = 0; mi < 4; ++mi)
        #pragma unroll
        for (int ni = 0; ni < 2; ++ni)
            #pragma unroll
            for (int j = 0; j < 4; ++j) {
                int r = wm * 64 + mi * 16 + hi4 * 4 + j;
                int c = wn * 32 + ni * 16 + lo4;
                bounce[r][c] = fmaxf(acc[mi][ni][j] + bo[n0 + c], 0.f);
            }
    __syncthreads();
    #pragma unroll
    for (int i = 0; i < 8; ++i) {
        int ch = i * 256 + tid;
        int row = ch >> 4, c4 = (ch & 15) * 4;
        *(f32x4*)(out + (size_t)(s0 + row) * 256 + n0 + c4) = *(f32x4*)&bounce[row][c4];
    }
}

extern "C" void kernel_launch(void* const* d_in, const int* in_sizes, int n_in,
                              void* d_out, int out_size, void* d_ws, size_t ws_size,
                              hipStream_t stream) {
    const float* x    = (const float*)d_in[0];
    const float* mask = (const float*)d_in[1];
    const float* Wv   = (const float*)d_in[2];
    const float* bv   = (const float*)d_in[3];
    const float* Wk   = (const float*)d_in[4];
    const float* bk   = (const float*)d_in[5];
    const float* Wq   = (const float*)d_in[6];
    const float* bq   = (const float*)d_in[7];
    const float* Wo   = (const float*)d_in[8];
    const float* bo   = (const float*)d_in[9];
    float* out = (float*)d_out;

    char* ws = (char*)d_ws;
    short* Wt   = (short*)ws;                                 // 512 KB @ 0
    u64*   mpW  = (u64*)(ws + (512 << 10));                   // 4 MB  @ 0.5 MB
    short* qB   = (short*)(ws + (4608 << 10));                // 16 MB @ 4.5 MB
    short* kB   = qB  + (size_t)32768 * 256;                  // @ 20.5 MB
    short* vtB  = kB  + (size_t)32768 * 256;                  // @ 36.5 MB
    short* avB  = vtB + (size_t)32768 * 256;                  // @ 52.5 MB (ends 68.5 MB)
    (void)in_sizes; (void)n_in; (void)out_size; (void)ws_size;

    mask_pack<<<4096, 256, 0, stream>>>(mask, mpW);
    prep_w<<<1024, 256, 0, stream>>>(Wq, Wk, Wv, Wo, Wt);
    qkv_gemm<<<1024, 256, 0, stream>>>(x, Wt, bq, bk, bv, qB, kB, vtB);
    attn<<<256, 512, 0, stream>>>(qB, kB, vtB, mpW, avB);
    out_gemm<<<1024, 256, 0, stream>>>(avB, Wt + 3 * 65536, bo, out);
}

// Round 13
// 123.707 us; speedup vs baseline: 1.2095x; 1.2095x over previous
//
#include <hip/hip_runtime.h>

// Pipeline: prep_w -> qkv_gemm (fused Q,K,V; K & V^T written XOR-swizzled)
//           -> attn_fused (flash with in-loop coalesced mask stream + in-register
//              ballot packing; epilogue fuses the output GEMM: attv -> LDS (reusing
//              K/V buffers), Wo^T staged per chunk, relu(.@Wo^T+bo) -> f32 out).
// All matmul compute in bf16 MFMA (16x16x32), f32 accumulate. Output f32.

typedef __attribute__((ext_vector_type(4))) float    f32x4;
typedef __attribute__((ext_vector_type(8))) short    s16x8;
typedef __attribute__((ext_vector_type(4))) short    s16x4;
typedef unsigned long long u64;

__device__ __forceinline__ short f2b(float f) {
    union { float f; unsigned u; } v; v.f = f;
    unsigned r = v.u + 0x7FFFu + ((v.u >> 16) & 1u);
    return (short)(r >> 16);
}

__device__ __forceinline__ void gl_lds16(const short* g, short* l) {
    __builtin_amdgcn_global_load_lds(
        (const __attribute__((address_space(1))) unsigned int*)g,
        (__attribute__((address_space(3))) unsigned int*)l, 16, 0, 0);
}

// ---- Wt[w][n][k] = (bf16) W_w[k][n], w order {q,k,v,o} ----
__global__ void prep_w(const float* __restrict__ Wq, const float* __restrict__ Wk,
                       const float* __restrict__ Wv, const float* __restrict__ Wo,
                       short* __restrict__ Wt) {
    int idx = blockIdx.x * 256 + threadIdx.x;       // 4 * 65536 total
    int w = idx >> 16, rem = idx & 65535;
    int n = rem >> 8, kk = rem & 255;
    const float* W = (w == 0) ? Wq : (w == 1) ? Wk : (w == 2) ? Wv : Wo;
    Wt[idx] = f2b(W[kk * 256 + n]);
}

// ---- fused QKV projection: x[32768,256] f32 @ W^T -> relu -> bf16 ----
// q stored [seq][h] linear; k stored [seq][h] with 16B-chunk low3 XOR (seq&7);
// v stored transposed Vt[b][h][seq] with 16B-chunk low3 XOR (h&7).
__global__ __launch_bounds__(256) void qkv_gemm(
        const float* __restrict__ x, const short* __restrict__ Wt,
        const float* __restrict__ bq, const float* __restrict__ bk, const float* __restrict__ bv,
        short* __restrict__ qO, short* __restrict__ kO, short* __restrict__ vtO) {
    __shared__ short a_lds[128][72];        // x tile bf16 (also reused as epilogue bounce)
    __shared__ short b_lds[3][64][72];      // W^T tiles
    const int tid = threadIdx.x;
    const int bm = blockIdx.x >> 2, bn = blockIdx.x & 3;
    const int s0 = bm * 128, n0 = bn * 64;
    const int wid = tid >> 6, l = tid & 63, lo4 = l & 15, hi4 = l >> 4;
    const int wm = wid >> 1, wn = wid & 1;

    f32x4 acc[3][4][2];
    #pragma unroll
    for (int w = 0; w < 3; ++w)
        #pragma unroll
        for (int mi = 0; mi < 4; ++mi)
            #pragma unroll
            for (int ni = 0; ni < 2; ++ni)
                acc[w][mi][ni] = (f32x4){0.f, 0.f, 0.f, 0.f};

    for (int kt = 0; kt < 4; ++kt) {
        const int k0 = kt * 64;
        #pragma unroll
        for (int i = 0; i < 8; ++i) {                       // stage A: 128x64 f32 -> bf16
            int ch = i * 256 + tid;
            int row = ch >> 4, c4 = (ch & 15) * 4;
            f32x4 xv = *(const f32x4*)(x + (size_t)(s0 + row) * 256 + k0 + c4);
            s16x4 pk = { f2b(xv.x), f2b(xv.y), f2b(xv.z), f2b(xv.w) };
            *(s16x4*)&a_lds[row][c4] = pk;
        }
        #pragma unroll
        for (int w = 0; w < 3; ++w) {                       // stage B: 3 x 64x64 bf16
            #pragma unroll
            for (int i = 0; i < 2; ++i) {
                int ch = i * 256 + tid;
                int n = ch >> 3, c8 = (ch & 7) * 8;
                *(s16x8*)&b_lds[w][n][c8] =
                    *(const s16x8*)(Wt + (size_t)w * 65536 + (size_t)(n0 + n) * 256 + k0 + c8);
            }
        }
        __syncthreads();
        s16x8 af[4][2];
        #pragma unroll
        for (int mi = 0; mi < 4; ++mi)
            #pragma unroll
            for (int kk = 0; kk < 2; ++kk)
                af[mi][kk] = *(s16x8*)&a_lds[wm * 64 + mi * 16 + lo4][kk * 32 + hi4 * 8];
        #pragma unroll
        for (int w = 0; w < 3; ++w)
            #pragma unroll
            for (int ni = 0; ni < 2; ++ni)
                #pragma unroll
                for (int kk = 0; kk < 2; ++kk) {
                    s16x8 bfr = *(s16x8*)&b_lds[w][wn * 32 + ni * 16 + lo4][kk * 32 + hi4 * 8];
                    #pragma unroll
                    for (int mi = 0; mi < 4; ++mi)
                        acc[w][mi][ni] = __builtin_amdgcn_mfma_f32_16x16x32_bf16(
                            af[mi][kk], bfr, acc[w][mi][ni], 0, 0, 0);
                }
        __syncthreads();
    }

    const float* bias[3] = { bq, bk, bv };
    for (int w = 0; w < 3; ++w) {
        #pragma unroll
        for (int mi = 0; mi < 4; ++mi)
            #pragma unroll
            for (int ni = 0; ni < 2; ++ni)
                #pragma unroll
                for (int j = 0; j < 4; ++j) {
                    int r = wm * 64 + mi * 16 + hi4 * 4 + j;
                    int c = wn * 32 + ni * 16 + lo4;
                    float v = acc[w][mi][ni][j] + bias[w][n0 + c];
                    a_lds[r][c] = f2b(fmaxf(v, 0.f));
                }
        __syncthreads();
        if (w == 0) {
            #pragma unroll
            for (int i = 0; i < 4; ++i) {
                int ch = i * 256 + tid;
                int row = ch >> 3, c8 = (ch & 7) * 8;
                *(s16x8*)(qO + (size_t)(s0 + row) * 256 + n0 + c8) = *(s16x8*)&a_lds[row][c8];
            }
        } else if (w == 1) {
            #pragma unroll
            for (int i = 0; i < 4; ++i) {
                int ch = i * 256 + tid;
                int row = ch >> 3, c8 = (ch & 7) * 8;
                int swz = ((c8 >> 3) ^ (row & 7)) * 8;      // seq-keyed chunk XOR
                *(s16x8*)(kO + (size_t)(s0 + row) * 256 + n0 + swz) = *(s16x8*)&a_lds[row][c8];
            }
        } else {
            int bb = s0 >> 10, nn = s0 & 1023;              // block spans a single batch
            #pragma unroll
            for (int i = 0; i < 4; ++i) {
                int ch = i * 256 + tid;
                int h = ch >> 4, sc = (ch & 15) * 8;
                s16x8 t;
                #pragma unroll
                for (int e = 0; e < 8; ++e) t[e] = a_lds[sc + e][h];
                int cil = sc >> 3;                          // 0..15
                int swz = (cil & 8) | ((cil & 7) ^ ((n0 + h) & 7));   // h-keyed chunk XOR
                *(s16x8*)(vtO + ((size_t)bb * 256 + n0 + h) * 1024 + nn + swz * 8) = t;
            }
        }
        __syncthreads();
    }
}

// ---- fused flash attention + output GEMM ----
// Flash phase (r8-validated): 8 waves, Q-tile 128, dbuf LDS K/V via global_load_lds,
// counted vmcnt; mask streamed as coalesced f32x4 one tile ahead, packed in-register
// via __ballot. Epilogue: normalized attv (bf16) -> av_lds (over dead K/V buffers),
// then out = relu(av @ Wo^T + bo) with Wo^T staged per 64-col chunk. No attv/out_gemm
// round-trip through HBM.
__global__ __launch_bounds__(512) void attn_fused(
        const short* __restrict__ q, const short* __restrict__ k,
        const short* __restrict__ vt, const float* __restrict__ mask,
        const short* __restrict__ WtO, const float* __restrict__ bo,
        float* __restrict__ out) {
    __shared__ short SM[65536];             // flash: kbuf[2]|vbuf[2]; epilogue: av|wo
    __shared__ short p_lds[8][16][72];      // per-wave P relayout / attv bounce
    const int tid = threadIdx.x, wid = tid >> 6, l = tid & 63;
    const int lo4 = l & 15, hi4 = l >> 4;
    const int bid = blockIdx.x;
    const int swz = (bid & 7) * 32 + (bid >> 3);    // XCD-chunked: 4 batches per XCD
    const int b = swz >> 3, qb = swz & 7;
    const int q0 = qb * 128 + wid * 16;
    const size_t bq0 = (size_t)b * 1024 + qb * 128;
    const size_t bq_row = (size_t)b * 1024 + q0;

    const short* kb  = k  + (size_t)b * 1024 * 256;
    const short* vtg = vt + (size_t)b * 256 * 1024;
    const float* mtb = mask + bq_row * 1024;        // wave's 16 mask rows

#define KBUF(bufi) (SM + (bufi) * 16384)
#define VBUF(bufi) (SM + 32768 + (bufi) * 16384)
#define STAGE_K(bufi, c0_) do { const short* sg_ = kb + (size_t)(c0_) * 256;          \
    _Pragma("unroll") for (int i_ = 0; i_ < 4; ++i_) { int cb_ = i_ * 512 + wid * 64; \
        gl_lds16(sg_ + (size_t)(cb_ + l) * 8, KBUF(bufi) + cb_ * 8); } } while (0)
#define STAGE_V(bufi, c0_) do {                                                       \
    _Pragma("unroll") for (int i_ = 0; i_ < 4; ++i_) { int cb_ = i_ * 512 + wid * 64; \
        int ch_ = cb_ + l; int h_ = ch_ >> 3, cc_ = ch_ & 7;                          \
        gl_lds16(vtg + (size_t)h_ * 1024 + (c0_) + cc_ * 8, VBUF(bufi) + cb_ * 8); } } while (0)
// 4 coalesced f32x4 loads: dst[i] = mask[row i*4+hi4][c0 + lo4*4 .. +3] of wave's tile
#define LOAD_MASK(dst, c0_) do {                                                      \
    _Pragma("unroll") for (int i_ = 0; i_ < 4; ++i_)                                  \
        dst[i_] = *(const f32x4*)(mtb + (size_t)(i_ * 4 + hi4) * 1024 + (c0_) + lo4 * 4); } while (0)

    s16x8 qf[8];
    {
        const short* qp = q + (bq_row + lo4) * 256 + hi4 * 8;
        #pragma unroll
        for (int t = 0; t < 8; ++t) qf[t] = *(const s16x8*)(qp + t * 32);
    }
    f32x4 oacc[16];
    #pragma unroll
    for (int t = 0; t < 16; ++t) oacc[t] = (f32x4){0.f, 0.f, 0.f, 0.f};
    float m_run[4] = { -1e30f, -1e30f, -1e30f, -1e30f };
    float l_run[4] = { 0.f, 0.f, 0.f, 0.f };
    f32x4 mkc[4], mkn[4];                   // raw mask tile dbuf (f32x4 per lane)

    // prologue: stage tile 0 (K: 4 loads, mask: 4, V: 4)
    STAGE_K(0, 0);
    LOAD_MASK(mkc, 0);
    STAGE_V(0, 0);

    for (int t = 0; t < 16; ++t) {
        const int cur = t & 1;
        const int c0 = t * 64;
        if (t < 15) {
            STAGE_K(cur ^ 1, c0 + 64);                      // +4 vmem
            LOAD_MASK(mkn, c0 + 64);                        // +4 vmem
            // younger-than-K[t]: mask[t](4) + V[t](4) + K[t+1](4) + mask[t+1](4) = 16
            asm volatile("s_waitcnt vmcnt(16)" ::: "memory");
        } else {
            asm volatile("s_waitcnt vmcnt(8)" ::: "memory");
        }
        __builtin_amdgcn_s_barrier();
        // ---- QK^T on kbuf[cur] ----
        f32x4 s[4];
        #pragma unroll
        for (int ct = 0; ct < 4; ++ct) s[ct] = (f32x4){0.f, 0.f, 0.f, 0.f};
        __builtin_amdgcn_s_setprio(1);
        #pragma unroll
        for (int ct = 0; ct < 4; ++ct) {
            int row = ct * 16 + lo4, rx = row & 7;
            #pragma unroll
            for (int tt = 0; tt < 8; ++tt) {
                int ch = tt * 4 + hi4;
                int sc = (ch & 24) | ((ch & 7) ^ rx);
                s16x8 kf = *(s16x8*)(KBUF(cur) + row * 256 + sc * 8);
                s[ct] = __builtin_amdgcn_mfma_f32_16x16x32_bf16(qf[tt], kf, s[ct], 0, 0, 0);
            }
        }
        __builtin_amdgcn_s_setprio(0);
        // ---- in-register mask pack: 16 ballots ----
        u64 bw[4][4];
        #pragma unroll
        for (int i = 0; i < 4; ++i) {
            bw[i][0] = __ballot(mkc[i].x != 0.f);
            bw[i][1] = __ballot(mkc[i].y != 0.f);
            bw[i][2] = __ballot(mkc[i].z != 0.f);
            bw[i][3] = __ballot(mkc[i].w != 0.f);
        }
        const int cc = lo4 & 3;
        u64 w0 = (cc == 0) ? bw[0][0] : (cc == 1) ? bw[0][1] : (cc == 2) ? bw[0][2] : bw[0][3];
        u64 w1 = (cc == 0) ? bw[1][0] : (cc == 1) ? bw[1][1] : (cc == 2) ? bw[1][2] : bw[1][3];
        u64 w2 = (cc == 0) ? bw[2][0] : (cc == 1) ? bw[2][1] : (cc == 2) ? bw[2][2] : bw[2][3];
        u64 w3 = (cc == 0) ? bw[3][0] : (cc == 1) ? bw[3][1] : (cc == 2) ? bw[3][2] : bw[3][3];
        u64 wsel = (hi4 == 0) ? w0 : (hi4 == 1) ? w1 : (hi4 == 2) ? w2 : w3;
        const unsigned sh0 = (unsigned)(lo4 >> 2);
        float sm[4][4];
        #pragma unroll
        for (int j = 0; j < 4; ++j) {
            unsigned wsx = (unsigned)(wsel >> (j * 16 + sh0));
            sm[0][j] = (wsx & 1u)    ? s[0][j] : -1e30f;
            sm[1][j] = (wsx & 16u)   ? s[1][j] : -1e30f;
            sm[2][j] = (wsx & 256u)  ? s[2][j] : -1e30f;
            sm[3][j] = (wsx & 4096u) ? s[3][j] : -1e30f;
        }
        float scale[4], p[4][4];
        #pragma unroll
        for (int j = 0; j < 4; ++j) {
            float tmx = fmaxf(fmaxf(sm[0][j], sm[1][j]), fmaxf(sm[2][j], sm[3][j]));
            tmx = fmaxf(tmx, __shfl_xor(tmx, 1));
            tmx = fmaxf(tmx, __shfl_xor(tmx, 2));
            tmx = fmaxf(tmx, __shfl_xor(tmx, 4));
            tmx = fmaxf(tmx, __shfl_xor(tmx, 8));
            float mnew = fmaxf(m_run[j], tmx);
            scale[j] = __expf(m_run[j] - mnew);
            m_run[j] = mnew;
            float su = 0.f;
            #pragma unroll
            for (int ct = 0; ct < 4; ++ct) { p[ct][j] = __expf(sm[ct][j] - mnew); su += p[ct][j]; }
            su += __shfl_xor(su, 1);
            su += __shfl_xor(su, 2);
            su += __shfl_xor(su, 4);
            su += __shfl_xor(su, 8);
            l_run[j] = l_run[j] * scale[j] + su;
        }
        #pragma unroll
        for (int tt = 0; tt < 16; ++tt)
            #pragma unroll
            for (int j = 0; j < 4; ++j) oacc[tt][j] *= scale[j];
        // ---- P (D-layout) -> per-wave LDS -> A-fragment ----
        #pragma unroll
        for (int ct = 0; ct < 4; ++ct)
            #pragma unroll
            for (int j = 0; j < 4; ++j)
                p_lds[wid][hi4 * 4 + j][ct * 16 + lo4] = f2b(p[ct][j]);
        asm volatile("s_waitcnt lgkmcnt(0)" ::: "memory");
        __builtin_amdgcn_sched_barrier(0);
        s16x8 pa0 = *(s16x8*)&p_lds[wid][lo4][hi4 * 8];
        s16x8 pa1 = *(s16x8*)&p_lds[wid][lo4][32 + hi4 * 8];
        // ---- issue next V stage, then wait for V[t] (counted) ----
        if (t < 15) {
            STAGE_V(cur ^ 1, c0 + 64);                      // +4 vmem
            asm volatile("s_waitcnt vmcnt(12)" ::: "memory");
        } else {
            asm volatile("s_waitcnt vmcnt(0)" ::: "memory");
        }
        __builtin_amdgcn_s_barrier();
        // ---- PV on vbuf[cur] ----
        __builtin_amdgcn_s_setprio(1);
        #pragma unroll
        for (int nt = 0; nt < 16; ++nt) {
            int h = nt * 16 + lo4, hx = h & 7;
            s16x8 vf0 = *(s16x8*)(VBUF(cur) + h * 64 + (hi4 ^ hx) * 8);
            s16x8 vf1 = *(s16x8*)(VBUF(cur) + h * 64 + ((hi4 + 4) ^ hx) * 8);
            oacc[nt] = __builtin_amdgcn_mfma_f32_16x16x32_bf16(pa0, vf0, oacc[nt], 0, 0, 0);
            oacc[nt] = __builtin_amdgcn_mfma_f32_16x16x32_bf16(pa1, vf1, oacc[nt], 0, 0, 0);
        }
        __builtin_amdgcn_s_setprio(0);
        // ---- rotate mask regs ----
        if (t < 15) {
            #pragma unroll
            for (int i = 0; i < 4; ++i) mkc[i] = mkn[i];
        }
    }
    __syncthreads();                        // flash done: K/V buffers are dead

    // ---- normalize -> bf16 attv into av_lds[128][264] (over dead K/V region) ----
    float inv[4];
    #pragma unroll
    for (int j = 0; j < 4; ++j) inv[j] = 1.f / l_run[j];
    #pragma unroll
    for (int g = 0; g < 4; ++g) {
        asm volatile("s_waitcnt lgkmcnt(0)" ::: "memory");  // prior pass reads done
        #pragma unroll
        for (int ntl = 0; ntl < 4; ++ntl)
            #pragma unroll
            for (int j = 0; j < 4; ++j)
                p_lds[wid][hi4 * 4 + j][ntl * 16 + lo4] = f2b(oacc[g * 4 + ntl][j] * inv[j]);
        asm volatile("s_waitcnt lgkmcnt(0)" ::: "memory");
        __builtin_amdgcn_sched_barrier(0);
        s16x8 r0 = *(s16x8*)&p_lds[wid][lo4][hi4 * 16];
        s16x8 r1 = *(s16x8*)&p_lds[wid][lo4][hi4 * 16 + 8];
        int arow = wid * 16 + lo4;
        *(s16x8*)&SM[arow * 264 + g * 64 + hi4 * 16]     = r0;
        *(s16x8*)&SM[arow * 264 + g * 64 + hi4 * 16 + 8] = r1;
    }
    // ---- stage Wo^T chunk 0 into wo region (SM+33792, [64][264]) ----
    short* wo = SM + 33792;
    #pragma unroll
    for (int i = 0; i < 4; ++i) {
        int idx = i * 512 + tid;
        int n = idx >> 5, c8 = (idx & 31) * 8;
        *(s16x8*)&wo[n * 264 + c8] = *(const s16x8*)(WtO + (size_t)n * 256 + c8);
    }
    __syncthreads();                        // av + wo[chunk0] visible block-wide

    // ---- output GEMM: out[128][256] = relu(av @ Wo^T + bo), 4 chunks of 64 cols ----
    for (int chk = 0; chk < 4; ++chk) {
        const int n0 = chk * 64;
        f32x4 acc2[4];
        #pragma unroll
        for (int ni = 0; ni < 4; ++ni) acc2[ni] = (f32x4){0.f, 0.f, 0.f, 0.f};
        #pragma unroll
        for (int kk = 0; kk < 8; ++kk) {
            s16x8 af = *(s16x8*)&SM[(wid * 16 + lo4) * 264 + kk * 32 + hi4 * 8];
            #pragma unroll
            for (int ni = 0; ni < 4; ++ni) {
                s16x8 bf = *(s16x8*)&wo[(ni * 16 + lo4) * 264 + kk * 32 + hi4 * 8];
                acc2[ni] = __builtin_amdgcn_mfma_f32_16x16x32_bf16(af, bf, acc2[ni], 0, 0, 0);
            }
        }
        #pragma unroll
        for (int ni = 0; ni < 4; ++ni) {
            float bv = bo[n0 + ni * 16 + lo4];
            #pragma unroll
            for (int j = 0; j < 4; ++j) {
                int r = wid * 16 + hi4 * 4 + j;
                out[(bq0 + r) * 256 + n0 + ni * 16 + lo4] = fmaxf(acc2[ni][j] + bv, 0.f);
            }
        }
        if (chk < 3) {
            __syncthreads();                // all waves done reading wo[chk]
            #pragma unroll
            for (int i = 0; i < 4; ++i) {
                int idx = i * 512 + tid;
                int n = idx >> 5, c8 = (idx & 31) * 8;
                *(s16x8*)&wo[n * 264 + c8] =
                    *(const s16x8*)(WtO + (size_t)(n0 + 64 + n) * 256 + c8);
            }
            __syncthreads();                // wo[chk+1] visible
        }
    }
#undef KBUF
#undef VBUF
#undef STAGE_K
#undef STAGE_V
#undef LOAD_MASK
}

extern "C" void kernel_launch(void* const* d_in, const int* in_sizes, int n_in,
                              void* d_out, int out_size, void* d_ws, size_t ws_size,
                              hipStream_t stream) {
    const float* x    = (const float*)d_in[0];
    const float* mask = (const float*)d_in[1];
    const float* Wv   = (const float*)d_in[2];
    const float* bv   = (const float*)d_in[3];
    const float* Wk   = (const float*)d_in[4];
    const float* bk   = (const float*)d_in[5];
    const float* Wq   = (const float*)d_in[6];
    const float* bq   = (const float*)d_in[7];
    const float* Wo   = (const float*)d_in[8];
    const float* bo   = (const float*)d_in[9];
    float* out = (float*)d_out;

    char* ws = (char*)d_ws;
    short* Wt   = (short*)ws;                                 // 512 KB @ 0
    short* qB   = (short*)(ws + (1 << 20));                   // 16 MB @ 1 MB
    short* kB   = qB  + (size_t)32768 * 256;                  // @ 17 MB
    short* vtB  = kB  + (size_t)32768 * 256;                  // @ 33 MB (ends 49 MB)
    (void)in_sizes; (void)n_in; (void)out_size; (void)ws_size;

    prep_w<<<1024, 256, 0, stream>>>(Wq, Wk, Wv, Wo, Wt);
    qkv_gemm<<<1024, 256, 0, stream>>>(x, Wt, bq, bk, bv, qB, kB, vtB);
    attn_fused<<<256, 512, 0, stream>>>(qB, kB, vtB, mask, Wt + 3 * 65536, bo, out);
}